// Round 10
// baseline (170.978 us; speedup 1.0000x reference)
//
#include <hip/hip_runtime.h>
#include <math.h>

#define TPB 64      // ONE wave per workgroup
#define NT_MAX 8    // tiles per block (software pipeline depth 2)

// XOR-swizzle on linear LDS byte offset A (tile = 2 rows x 1024 f32 = 8 KB).
// key = ((A>>8)^(A>>11))&7 applied to slot bits [4:7).  Involution.
// swz does NOT commute with '+': within a run whose unswizzled base has bits
// 4-6 clear and whose key bits are constant, swz(A+16k) = swz(A)^16k.
// Also: swz(X^128) = swz(X)^128 (bit 7 is not part of the key).
__device__ __forceinline__ unsigned swz(unsigned A) {
    return A ^ ((((A >> 8) ^ (A >> 11)) & 7u) << 4);
}

__device__ __forceinline__ float4 ldsrd(const char* ldsb, unsigned A) {
    return *(const float4*)(ldsb + A);
}

// One stage of block size N (512/256/128) in LDS. Oct-task per thread:
// 8 consecutive pair-indices in both halves of one block -> 32 outputs.
// BARRIER-FREE: the (single) wave owns the whole LDS tile; a wave's DS
// instructions execute in order, so all cross-lane RAW/WAR hazards through
// LDS are ordered without __syncthreads.
template<int N>
__device__ __forceinline__ void lds_stage(char* ldsb, unsigned rb, unsigned tt,
                                          float p, float p1, float p2) {
    constexpr unsigned H = N / 2;
    constexpr int L2 = (N == 512) ? 4 : (N == 256) ? 3 : 2;   // log2(N/32)
    const unsigned b  = tt >> L2;
    const unsigned s  = tt & ((N / 32) - 1);
    const unsigned u0 = s * 8u;
    const unsigned bc = b * (unsigned)N;

    const unsigned Aj0  = swz(rb + 4u * (bc + u0));
    const unsigned Aj1  = swz(rb + 4u * (bc + H + u0));
    const unsigned Ajm0 = swz(rb + 4u * (bc + H - 8 - u0));
    const unsigned Ajm1 = swz(rb + 4u * (bc + N - 8 - u0));
    const unsigned Ae   = swz(rb + 4u * (bc + 2 * u0));
    const unsigned Aem  = swz(rb + 4u * (bc + 2 * H - 16 - 2 * u0));

    float j0[8], j1[8], jm0[8], jm1[8], e[16], em[16];
    *(float4*)&j0[0]  = ldsrd(ldsb, Aj0);        *(float4*)&j0[4]  = ldsrd(ldsb, Aj0 ^ 16u);
    *(float4*)&j1[0]  = ldsrd(ldsb, Aj1);        *(float4*)&j1[4]  = ldsrd(ldsb, Aj1 ^ 16u);
    *(float4*)&jm0[0] = ldsrd(ldsb, Ajm0);       *(float4*)&jm0[4] = ldsrd(ldsb, Ajm0 ^ 16u);
    *(float4*)&jm1[0] = ldsrd(ldsb, Ajm1);       *(float4*)&jm1[4] = ldsrd(ldsb, Ajm1 ^ 16u);
    *(float4*)&e[0]   = ldsrd(ldsb, Ae);         *(float4*)&e[4]   = ldsrd(ldsb, Ae ^ 16u);
    *(float4*)&e[8]   = ldsrd(ldsb, Ae ^ 32u);   *(float4*)&e[12]  = ldsrd(ldsb, Ae ^ 48u);
    *(float4*)&em[0]  = ldsrd(ldsb, Aem);        *(float4*)&em[4]  = ldsrd(ldsb, Aem ^ 16u);
    *(float4*)&em[8]  = ldsrd(ldsb, Aem ^ 32u);  *(float4*)&em[12] = ldsrd(ldsb, Aem ^ 48u);

    #pragma unroll
    for (int du = 0; du < 8; ++du) {
        {   // lo half
            float yj = j0[du], yjm = jm0[7 - du];
            float yej = e[2 * du], yejm = em[14 - 2 * du];
            float a0 = fmaf(p, yej - yj, yj);
            float a1 = fmaf(p, yejm - yjm, yjm);
            float d  = a1 - a0;
            j0[du]      = fmaf(p1, d, a0);
            jm0[7 - du] = fmaf(p1, -d, a1);
        }
        {   // hi half
            float zj = j1[du], zjm = jm1[7 - du];
            float zej = e[2 * du + 1], zejm = em[15 - 2 * du];
            float a0 = fmaf(p, zej - zj, zj);
            float a1 = fmaf(p, zejm - zjm, zjm);
            float d  = a1 - a0;
            j1[du]      = fmaf(p2, d, a0);
            jm1[7 - du] = fmaf(p2, -d, a1);
        }
    }
    // writes reuse the j-read addresses; same-wave DS ordering -> no barrier
    *(float4*)(ldsb + Aj0)          = *(const float4*)&j0[0];
    *(float4*)(ldsb + (Aj0 ^ 16u))  = *(const float4*)&j0[4];
    *(float4*)(ldsb + Aj1)          = *(const float4*)&j1[0];
    *(float4*)(ldsb + (Aj1 ^ 16u))  = *(const float4*)&j1[4];
    *(float4*)(ldsb + Ajm0)         = *(const float4*)&jm0[0];
    *(float4*)(ldsb + (Ajm0 ^ 16u)) = *(const float4*)&jm0[4];
    *(float4*)(ldsb + Ajm1)         = *(const float4*)&jm1[0];
    *(float4*)(ldsb + (Ajm1 ^ 16u)) = *(const float4*)&jm1[4];
}

// Stage of block size N <= 32 fully inside one thread's 32-float chunk.
template<int N>
__device__ __forceinline__ void reg_stage(float* arr, float p, float p1, float p2) {
    constexpr int H = N / 2;
    float tmp[32];
    #pragma unroll
    for (int bb = 0; bb < 32; bb += N) {
        #pragma unroll
        for (int u = 0; u < N / 4; ++u) {
            {   // lo half pair
                int j = bb + u, jm = bb + H - 1 - u;
                int ej = bb + 2 * u, ejm = bb + 2 * H - 2 - 2 * u;
                float a0 = fmaf(p, arr[ej]  - arr[j],  arr[j]);
                float a1 = fmaf(p, arr[ejm] - arr[jm], arr[jm]);
                tmp[j]  = fmaf(p1, a1 - a0, a0);
                tmp[jm] = fmaf(p1, a0 - a1, a1);
            }
            {   // hi half pair
                int j = bb + H + u, jm = bb + 2 * H - 1 - u;
                int ej = bb + 2 * u + 1, ejm = bb + 2 * H - 1 - 2 * u;
                float a0 = fmaf(p, arr[ej]  - arr[j],  arr[j]);
                float a1 = fmaf(p, arr[ejm] - arr[jm], arr[jm]);
                tmp[j]  = fmaf(p2, a1 - a0, a0);
                tmp[jm] = fmaf(p2, a0 - a1, a1);
            }
        }
    }
    #pragma unroll
    for (int v = 0; v < 32; ++v) arr[v] = tmp[v];
}

__global__ void bpp_prep(const float* __restrict__ logits, float* __restrict__ sp) {
    int i = threadIdx.x;
    if (i < 27) sp[i] = 1.0f / (1.0f + expf(-logits[i]));
}

template<bool USE_WS>
__global__ __launch_bounds__(TPB) void bpp_main(const float* __restrict__ x,
                                                float* __restrict__ out,
                                                const float* __restrict__ spws,
                                                const float* __restrict__ logits,
                                                int nt) {
    __shared__ float lds[2 * 1024 + 1024];      // one 8 KB tile buffer (+pad)
    char* ldsb = (char*)lds;
    const unsigned l = threadIdx.x;             // lane id (block == one wave)

    float prl[27];
    if constexpr (!USE_WS) {
        #pragma unroll
        for (int i = 0; i < 27; ++i) prl[i] = 1.0f / (1.0f + expf(-logits[i]));
    }
    #define PV(i) (USE_WS ? spws[(i)] : prl[(i)])

    const unsigned row = l >> 5, tt = l & 31u;
    const unsigned rb = row * 4096u;
    const size_t tile0 = (size_t)blockIdx.x * (unsigned)nt;

    // ---- prologue: prefetch tile 0 into registers ----
    float4 pf[8];
    {
        const float4* __restrict__ gin = (const float4*)(x + tile0 * 2048u) + l;
        #pragma unroll
        for (int k = 0; k < 8; ++k) pf[k] = gin[k * 64];
    }

    for (int it = 0; it < nt; ++it) {
        const size_t gofs = (tile0 + it) * 2048u;

        // ---- commit prefetched tile to LDS (swizzled dest) ----
        #pragma unroll
        for (int k = 0; k < 8; ++k) {
            unsigned A = (unsigned)k * 1024u + l * 16u;
            *(float4*)(ldsb + swz(A)) = pf[k];
        }

        // ---- issue next tile's loads NOW; latency hides under processing ----
        if (it + 1 < nt) {
            const float4* __restrict__ gin = (const float4*)(x + gofs + 2048u) + l;
            #pragma unroll
            for (int k = 0; k < 8; ++k) pf[k] = gin[k * 64];
        }

        // ---- stage 1024 (b=0 specialization), barrier-free ----
        {
            constexpr unsigned N = 1024, H = 512;
            const unsigned u0 = tt * 8u;
            const unsigned Aj0  = swz(rb + 4u * u0);
            const unsigned Aj1  = swz(rb + 4u * (H + u0));
            const unsigned Ajm0 = swz(rb + 4u * (H - 8 - u0));
            const unsigned Ajm1 = swz(rb + 4u * (N - 8 - u0));
            const unsigned Ae   = swz(rb + 4u * (2 * u0));
            const unsigned Aem  = swz(rb + 4u * (2 * H - 16 - 2 * u0));
            const float p = PV(24), p1 = PV(25), p2 = PV(26);

            float j0[8], j1[8], jm0[8], jm1[8], e[16], em[16];
            *(float4*)&j0[0]  = ldsrd(ldsb, Aj0);        *(float4*)&j0[4]  = ldsrd(ldsb, Aj0 ^ 16u);
            *(float4*)&j1[0]  = ldsrd(ldsb, Aj1);        *(float4*)&j1[4]  = ldsrd(ldsb, Aj1 ^ 16u);
            *(float4*)&jm0[0] = ldsrd(ldsb, Ajm0);       *(float4*)&jm0[4] = ldsrd(ldsb, Ajm0 ^ 16u);
            *(float4*)&jm1[0] = ldsrd(ldsb, Ajm1);       *(float4*)&jm1[4] = ldsrd(ldsb, Ajm1 ^ 16u);
            *(float4*)&e[0]   = ldsrd(ldsb, Ae);         *(float4*)&e[4]   = ldsrd(ldsb, Ae ^ 16u);
            *(float4*)&e[8]   = ldsrd(ldsb, Ae ^ 32u);   *(float4*)&e[12]  = ldsrd(ldsb, Ae ^ 48u);
            *(float4*)&em[0]  = ldsrd(ldsb, Aem);        *(float4*)&em[4]  = ldsrd(ldsb, Aem ^ 16u);
            *(float4*)&em[8]  = ldsrd(ldsb, Aem ^ 32u);  *(float4*)&em[12] = ldsrd(ldsb, Aem ^ 48u);

            #pragma unroll
            for (int du = 0; du < 8; ++du) {
                {
                    float yj = j0[du], yjm = jm0[7 - du];
                    float yej = e[2 * du], yejm = em[14 - 2 * du];
                    float a0 = fmaf(p, yej - yj, yj);
                    float a1 = fmaf(p, yejm - yjm, yjm);
                    float d  = a1 - a0;
                    j0[du]      = fmaf(p1, d, a0);
                    jm0[7 - du] = fmaf(p1, -d, a1);
                }
                {
                    float zj = j1[du], zjm = jm1[7 - du];
                    float zej = e[2 * du + 1], zejm = em[15 - 2 * du];
                    float a0 = fmaf(p, zej - zj, zj);
                    float a1 = fmaf(p, zejm - zjm, zjm);
                    float d  = a1 - a0;
                    j1[du]      = fmaf(p2, d, a0);
                    jm1[7 - du] = fmaf(p2, -d, a1);
                }
            }
            *(float4*)(ldsb + Aj0)          = *(const float4*)&j0[0];
            *(float4*)(ldsb + (Aj0 ^ 16u))  = *(const float4*)&j0[4];
            *(float4*)(ldsb + Aj1)          = *(const float4*)&j1[0];
            *(float4*)(ldsb + (Aj1 ^ 16u))  = *(const float4*)&j1[4];
            *(float4*)(ldsb + Ajm0)         = *(const float4*)&jm0[0];
            *(float4*)(ldsb + (Ajm0 ^ 16u)) = *(const float4*)&jm0[4];
            *(float4*)(ldsb + Ajm1)         = *(const float4*)&jm1[0];
            *(float4*)(ldsb + (Ajm1 ^ 16u)) = *(const float4*)&jm1[4];
        }
        lds_stage<512>(ldsb, rb, tt, PV(21), PV(22), PV(23));
        lds_stage<256>(ldsb, rb, tt, PV(18), PV(19), PV(20));
        lds_stage<128>(ldsb, rb, tt, PV(15), PV(16), PV(17));

        // ---- fused tail: stage 64 in registers + reg stages 32..4 ----
        {
            const unsigned q = tt & 1u;
            const unsigned Aown = swz(rb + 128u * tt);  // 128B-aligned, key const
            const unsigned Aoth = Aown ^ 128u;          // partner: bit7 not in key
            float own[32], oth[32];
            #pragma unroll
            for (int k = 0; k < 8; ++k) {
                *(float4*)&own[4 * k] = ldsrd(ldsb, Aown ^ (16u * k));
                *(float4*)&oth[4 * k] = ldsrd(ldsb, Aoth ^ (16u * k));
            }
            const float p = PV(12);
            const float q64 = q ? PV(14) : PV(13);
            float o[32];
            #pragma unroll
            for (int u = 0; u < 16; ++u) {
                float eja = q ? oth[2 * u + 1]  : own[2 * u];
                float ejb = q ? own[31 - 2 * u] : oth[30 - 2 * u];
                float yj = own[u], yjm = own[31 - u];
                float a0 = fmaf(p, eja - yj, yj);
                float a1 = fmaf(p, ejb - yjm, yjm);
                float d  = a1 - a0;
                o[u]      = fmaf(q64, d, a0);
                o[31 - u] = fmaf(q64, -d, a1);
            }
            reg_stage<32>(o, PV(9), PV(10), PV(11));
            reg_stage<16>(o, PV(6), PV(7),  PV(8));
            reg_stage< 8>(o, PV(3), PV(4),  PV(5));
            reg_stage< 4>(o, PV(0), PV(1),  PV(2));
            #pragma unroll
            for (int k = 0; k < 8; ++k)
                *(float4*)(ldsb + (Aown ^ (16u * k))) = *(const float4*)&o[4 * k];
        }

        // ---- exit: coalesced LDS -> global (1 KB per instruction) ----
        {
            float4* __restrict__ gout = (float4*)(out + gofs) + l;
            #pragma unroll
            for (int k = 0; k < 8; ++k) {
                unsigned A = (unsigned)k * 1024u + l * 16u;
                gout[k * 64] = *(const float4*)(ldsb + swz(A));
            }
        }
        // next iteration's ds_writes (WAR on these exit ds_reads) are ordered
        // by the wave's in-order DS pipe; prefetch loads' vmcnt is handled by
        // the compiler at the pf use point.
    }
    #undef PV
}

extern "C" void kernel_launch(void* const* d_in, const int* in_sizes, int n_in,
                              void* d_out, int out_size, void* d_ws, size_t ws_size,
                              hipStream_t stream) {
    const float* x      = (const float*)d_in[0];
    const float* logits = (const float*)d_in[1];
    float* out = (float*)d_out;
    int rows  = in_sizes[0] / 1024;
    int tiles = rows / 2;
    int nt = NT_MAX;
    while (nt > 1 && (tiles % nt)) nt >>= 1;
    int grid = tiles / nt;
    if (ws_size >= 27 * sizeof(float)) {
        float* sp = (float*)d_ws;
        bpp_prep<<<dim3(1), dim3(32), 0, stream>>>(logits, sp);
        bpp_main<true><<<dim3(grid), dim3(TPB), 0, stream>>>(x, out, sp, logits, nt);
    } else {
        bpp_main<false><<<dim3(grid), dim3(TPB), 0, stream>>>(x, out, nullptr, logits, nt);
    }
}

// Round 11
// 164.208 us; speedup vs baseline: 1.0412x; 1.0412x over previous
//
#include <hip/hip_runtime.h>
#include <math.h>

#define TPB 64      // ONE wave per workgroup
#define ROWS 2      // 8 KB LDS per block -> 20 blocks/CU (LDS-limited)

// XOR-swizzle on linear LDS byte offset A (tile = 2 rows x 1024 f32 = 8 KB).
// key = ((A>>8)^(A>>11))&7 applied to slot bits [4:7).  Involution.
// swz does NOT commute with '+': within a run whose unswizzled base has bits
// 4-6 clear and whose key bits are constant, swz(A+16k) = swz(A)^16k.
// Also: swz(X^128) = swz(X)^128 (bit 7 is not part of the key).
__device__ __forceinline__ unsigned swz(unsigned A) {
    return A ^ ((((A >> 8) ^ (A >> 11)) & 7u) << 4);
}

__device__ __forceinline__ float4 ldsrd(const char* ldsb, unsigned A) {
    return *(const float4*)(ldsb + A);
}

// One stage of block size N (512/256/128) in LDS. Oct-task per thread:
// 8 consecutive pair-indices in both halves of one block -> 32 outputs.
// BARRIER-FREE: the (single) wave owns the whole LDS tile; a wave's DS
// instructions execute in order, so all cross-lane RAW/WAR hazards through
// LDS are ordered without __syncthreads.
template<int N>
__device__ __forceinline__ void lds_stage(char* ldsb, unsigned rb, unsigned tt,
                                          float p, float p1, float p2) {
    constexpr unsigned H = N / 2;
    constexpr int L2 = (N == 512) ? 4 : (N == 256) ? 3 : 2;   // log2(N/32)
    const unsigned b  = tt >> L2;
    const unsigned s  = tt & ((N / 32) - 1);
    const unsigned u0 = s * 8u;
    const unsigned bc = b * (unsigned)N;

    const unsigned Aj0  = swz(rb + 4u * (bc + u0));
    const unsigned Aj1  = swz(rb + 4u * (bc + H + u0));
    const unsigned Ajm0 = swz(rb + 4u * (bc + H - 8 - u0));
    const unsigned Ajm1 = swz(rb + 4u * (bc + N - 8 - u0));
    const unsigned Ae   = swz(rb + 4u * (bc + 2 * u0));
    const unsigned Aem  = swz(rb + 4u * (bc + 2 * H - 16 - 2 * u0));

    float j0[8], j1[8], jm0[8], jm1[8], e[16], em[16];
    *(float4*)&j0[0]  = ldsrd(ldsb, Aj0);        *(float4*)&j0[4]  = ldsrd(ldsb, Aj0 ^ 16u);
    *(float4*)&j1[0]  = ldsrd(ldsb, Aj1);        *(float4*)&j1[4]  = ldsrd(ldsb, Aj1 ^ 16u);
    *(float4*)&jm0[0] = ldsrd(ldsb, Ajm0);       *(float4*)&jm0[4] = ldsrd(ldsb, Ajm0 ^ 16u);
    *(float4*)&jm1[0] = ldsrd(ldsb, Ajm1);       *(float4*)&jm1[4] = ldsrd(ldsb, Ajm1 ^ 16u);
    *(float4*)&e[0]   = ldsrd(ldsb, Ae);         *(float4*)&e[4]   = ldsrd(ldsb, Ae ^ 16u);
    *(float4*)&e[8]   = ldsrd(ldsb, Ae ^ 32u);   *(float4*)&e[12]  = ldsrd(ldsb, Ae ^ 48u);
    *(float4*)&em[0]  = ldsrd(ldsb, Aem);        *(float4*)&em[4]  = ldsrd(ldsb, Aem ^ 16u);
    *(float4*)&em[8]  = ldsrd(ldsb, Aem ^ 32u);  *(float4*)&em[12] = ldsrd(ldsb, Aem ^ 48u);

    #pragma unroll
    for (int du = 0; du < 8; ++du) {
        {   // lo half
            float yj = j0[du], yjm = jm0[7 - du];
            float yej = e[2 * du], yejm = em[14 - 2 * du];
            float a0 = fmaf(p, yej - yj, yj);
            float a1 = fmaf(p, yejm - yjm, yjm);
            float d  = a1 - a0;
            j0[du]      = fmaf(p1, d, a0);
            jm0[7 - du] = fmaf(p1, -d, a1);
        }
        {   // hi half
            float zj = j1[du], zjm = jm1[7 - du];
            float zej = e[2 * du + 1], zejm = em[15 - 2 * du];
            float a0 = fmaf(p, zej - zj, zj);
            float a1 = fmaf(p, zejm - zjm, zjm);
            float d  = a1 - a0;
            j1[du]      = fmaf(p2, d, a0);
            jm1[7 - du] = fmaf(p2, -d, a1);
        }
    }
    // writes reuse the j-read addresses; same-wave DS ordering -> no barrier
    *(float4*)(ldsb + Aj0)          = *(const float4*)&j0[0];
    *(float4*)(ldsb + (Aj0 ^ 16u))  = *(const float4*)&j0[4];
    *(float4*)(ldsb + Aj1)          = *(const float4*)&j1[0];
    *(float4*)(ldsb + (Aj1 ^ 16u))  = *(const float4*)&j1[4];
    *(float4*)(ldsb + Ajm0)         = *(const float4*)&jm0[0];
    *(float4*)(ldsb + (Ajm0 ^ 16u)) = *(const float4*)&jm0[4];
    *(float4*)(ldsb + Ajm1)         = *(const float4*)&jm1[0];
    *(float4*)(ldsb + (Ajm1 ^ 16u)) = *(const float4*)&jm1[4];
}

// Stage of block size N <= 32 fully inside one thread's 32-float chunk.
template<int N>
__device__ __forceinline__ void reg_stage(float* arr, float p, float p1, float p2) {
    constexpr int H = N / 2;
    float tmp[32];
    #pragma unroll
    for (int bb = 0; bb < 32; bb += N) {
        #pragma unroll
        for (int u = 0; u < N / 4; ++u) {
            {   // lo half pair
                int j = bb + u, jm = bb + H - 1 - u;
                int ej = bb + 2 * u, ejm = bb + 2 * H - 2 - 2 * u;
                float a0 = fmaf(p, arr[ej]  - arr[j],  arr[j]);
                float a1 = fmaf(p, arr[ejm] - arr[jm], arr[jm]);
                tmp[j]  = fmaf(p1, a1 - a0, a0);
                tmp[jm] = fmaf(p1, a0 - a1, a1);
            }
            {   // hi half pair
                int j = bb + H + u, jm = bb + 2 * H - 1 - u;
                int ej = bb + 2 * u + 1, ejm = bb + 2 * H - 1 - 2 * u;
                float a0 = fmaf(p, arr[ej]  - arr[j],  arr[j]);
                float a1 = fmaf(p, arr[ejm] - arr[jm], arr[jm]);
                tmp[j]  = fmaf(p2, a1 - a0, a0);
                tmp[jm] = fmaf(p2, a0 - a1, a1);
            }
        }
    }
    #pragma unroll
    for (int v = 0; v < 32; ++v) arr[v] = tmp[v];
}

__global__ void bpp_prep(const float* __restrict__ logits, float* __restrict__ sp) {
    int i = threadIdx.x;
    if (i < 27) sp[i] = 1.0f / (1.0f + expf(-logits[i]));
}

template<bool USE_WS>
__global__ __launch_bounds__(TPB) void bpp_main(const float* __restrict__ x,
                                                float* __restrict__ out,
                                                const float* __restrict__ spws,
                                                const float* __restrict__ logits) {
    __shared__ float lds[ROWS * 1024];
    char* ldsb = (char*)lds;
    const unsigned l = threadIdx.x;             // lane id (block == one wave)
    const size_t gbase = (size_t)blockIdx.x * (ROWS * 1024);

    float prl[27];
    if constexpr (!USE_WS) {
        #pragma unroll
        for (int i = 0; i < 27; ++i) prl[i] = 1.0f / (1.0f + expf(-logits[i]));
    }
    #define PV(i) (USE_WS ? spws[(i)] : prl[(i)])

    // ---- entry: coalesced global -> LDS (1 KB per instruction) ----
    {
        const float4* __restrict__ gin = (const float4*)(x + gbase) + l;
        #pragma unroll
        for (int k = 0; k < 8; ++k) {
            float4 v = gin[k * 64];
            unsigned A = (unsigned)k * 1024u + l * 16u;
            *(float4*)(ldsb + swz(A)) = v;
        }
    }
    // no barrier: same-wave DS ordering covers the stage-1024 reads below

    const unsigned row = l >> 5, tt = l & 31u;
    const unsigned rb = row * 4096u;

    // ---- stages n = 1024..128 in LDS (logits rows 8..5), barrier-free ----
    {
        // stage 1024 (b=0 specialization of lds_stage)
        constexpr unsigned N = 1024, H = 512;
        const unsigned u0 = tt * 8u;
        const unsigned Aj0  = swz(rb + 4u * u0);
        const unsigned Aj1  = swz(rb + 4u * (H + u0));
        const unsigned Ajm0 = swz(rb + 4u * (H - 8 - u0));
        const unsigned Ajm1 = swz(rb + 4u * (N - 8 - u0));
        const unsigned Ae   = swz(rb + 4u * (2 * u0));
        const unsigned Aem  = swz(rb + 4u * (2 * H - 16 - 2 * u0));
        const float p = PV(24), p1 = PV(25), p2 = PV(26);

        float j0[8], j1[8], jm0[8], jm1[8], e[16], em[16];
        *(float4*)&j0[0]  = ldsrd(ldsb, Aj0);        *(float4*)&j0[4]  = ldsrd(ldsb, Aj0 ^ 16u);
        *(float4*)&j1[0]  = ldsrd(ldsb, Aj1);        *(float4*)&j1[4]  = ldsrd(ldsb, Aj1 ^ 16u);
        *(float4*)&jm0[0] = ldsrd(ldsb, Ajm0);       *(float4*)&jm0[4] = ldsrd(ldsb, Ajm0 ^ 16u);
        *(float4*)&jm1[0] = ldsrd(ldsb, Ajm1);       *(float4*)&jm1[4] = ldsrd(ldsb, Ajm1 ^ 16u);
        *(float4*)&e[0]   = ldsrd(ldsb, Ae);         *(float4*)&e[4]   = ldsrd(ldsb, Ae ^ 16u);
        *(float4*)&e[8]   = ldsrd(ldsb, Ae ^ 32u);   *(float4*)&e[12]  = ldsrd(ldsb, Ae ^ 48u);
        *(float4*)&em[0]  = ldsrd(ldsb, Aem);        *(float4*)&em[4]  = ldsrd(ldsb, Aem ^ 16u);
        *(float4*)&em[8]  = ldsrd(ldsb, Aem ^ 32u);  *(float4*)&em[12] = ldsrd(ldsb, Aem ^ 48u);

        #pragma unroll
        for (int du = 0; du < 8; ++du) {
            {
                float yj = j0[du], yjm = jm0[7 - du];
                float yej = e[2 * du], yejm = em[14 - 2 * du];
                float a0 = fmaf(p, yej - yj, yj);
                float a1 = fmaf(p, yejm - yjm, yjm);
                float d  = a1 - a0;
                j0[du]      = fmaf(p1, d, a0);
                jm0[7 - du] = fmaf(p1, -d, a1);
            }
            {
                float zj = j1[du], zjm = jm1[7 - du];
                float zej = e[2 * du + 1], zejm = em[15 - 2 * du];
                float a0 = fmaf(p, zej - zj, zj);
                float a1 = fmaf(p, zejm - zjm, zjm);
                float d  = a1 - a0;
                j1[du]      = fmaf(p2, d, a0);
                jm1[7 - du] = fmaf(p2, -d, a1);
            }
        }
        *(float4*)(ldsb + Aj0)          = *(const float4*)&j0[0];
        *(float4*)(ldsb + (Aj0 ^ 16u))  = *(const float4*)&j0[4];
        *(float4*)(ldsb + Aj1)          = *(const float4*)&j1[0];
        *(float4*)(ldsb + (Aj1 ^ 16u))  = *(const float4*)&j1[4];
        *(float4*)(ldsb + Ajm0)         = *(const float4*)&jm0[0];
        *(float4*)(ldsb + (Ajm0 ^ 16u)) = *(const float4*)&jm0[4];
        *(float4*)(ldsb + Ajm1)         = *(const float4*)&jm1[0];
        *(float4*)(ldsb + (Ajm1 ^ 16u)) = *(const float4*)&jm1[4];
    }
    lds_stage<512>(ldsb, rb, tt, PV(21), PV(22), PV(23));
    lds_stage<256>(ldsb, rb, tt, PV(18), PV(19), PV(20));
    lds_stage<128>(ldsb, rb, tt, PV(15), PV(16), PV(17));

    // ---- fused tail: stage 64 in registers + reg stages 32..4 ----
    // Thread owns chunk tt (cols [32tt, 32tt+32)); its 64-block partner half
    // is chunk tt^1. q = tt&1 selects lo/hi-half math (branchless selects).
    {
        const unsigned q = tt & 1u;
        const unsigned Aown = swz(rb + 128u * tt);  // 128B-aligned, key const
        const unsigned Aoth = Aown ^ 128u;          // partner: bit7 not in key
        float own[32], oth[32];
        #pragma unroll
        for (int k = 0; k < 8; ++k) {
            *(float4*)&own[4 * k] = ldsrd(ldsb, Aown ^ (16u * k));
            *(float4*)&oth[4 * k] = ldsrd(ldsb, Aoth ^ (16u * k));
        }
        const float p = PV(12);
        const float q64 = q ? PV(14) : PV(13);
        float o[32];
        #pragma unroll
        for (int u = 0; u < 16; ++u) {
            float eja = q ? oth[2 * u + 1]  : own[2 * u];
            float ejb = q ? own[31 - 2 * u] : oth[30 - 2 * u];
            float yj = own[u], yjm = own[31 - u];
            float a0 = fmaf(p, eja - yj, yj);
            float a1 = fmaf(p, ejb - yjm, yjm);
            float d  = a1 - a0;
            o[u]      = fmaf(q64, d, a0);
            o[31 - u] = fmaf(q64, -d, a1);
        }
        reg_stage<32>(o, PV(9), PV(10), PV(11));
        reg_stage<16>(o, PV(6), PV(7),  PV(8));
        reg_stage< 8>(o, PV(3), PV(4),  PV(5));
        reg_stage< 4>(o, PV(0), PV(1),  PV(2));

        // ---- direct global store: lane writes its own 128B contiguous chunk.
        // Per store-instruction the wave covers the full 8 KB tile at 16B per
        // 64B line; lines are fully covered across the 8 stores and merge in
        // L2 (R4 measured WRITE_SIZE = 268 MB with this exact pattern).
        float* __restrict__ go = out + gbase + row * 1024u + 32u * tt;
        #pragma unroll
        for (int k = 0; k < 8; ++k)
            *(float4*)(go + 4 * k) = *(const float4*)&o[4 * k];
    }
    #undef PV
}

extern "C" void kernel_launch(void* const* d_in, const int* in_sizes, int n_in,
                              void* d_out, int out_size, void* d_ws, size_t ws_size,
                              hipStream_t stream) {
    const float* x      = (const float*)d_in[0];
    const float* logits = (const float*)d_in[1];
    float* out = (float*)d_out;
    int rows = in_sizes[0] / 1024;
    int grid = rows / ROWS;
    if (ws_size >= 27 * sizeof(float)) {
        float* sp = (float*)d_ws;
        bpp_prep<<<dim3(1), dim3(32), 0, stream>>>(logits, sp);
        bpp_main<true><<<dim3(grid), dim3(TPB), 0, stream>>>(x, out, sp, logits);
    } else {
        bpp_main<false><<<dim3(grid), dim3(TPB), 0, stream>>>(x, out, nullptr, logits);
    }
}

// Round 12
// 135.919 us; speedup vs baseline: 1.2579x; 1.2081x over previous
//
#include <hip/hip_runtime.h>
#include <math.h>

#define TPB 64       // ONE wave per workgroup
#define NBLK 5120    // 20 resident blocks/CU x 256 CU: persistent waves

// XOR-swizzle on linear LDS byte offset A (tile = 2 rows x 1024 f32 = 8 KB).
// key = ((A>>8)^(A>>11))&7 applied to slot bits [4:7).  Involution.
// swz does NOT commute with '+': within a run whose unswizzled base has bits
// 4-6 clear and whose key bits are constant, swz(A+16k) = swz(A)^16k.
// Also: swz(X^128) = swz(X)^128 (bit 7 is not part of the key).
__device__ __forceinline__ unsigned swz(unsigned A) {
    return A ^ ((((A >> 8) ^ (A >> 11)) & 7u) << 4);
}

__device__ __forceinline__ float4 ldsrd(const char* ldsb, unsigned A) {
    return *(const float4*)(ldsb + A);
}

// One stage of block size N (512/256/128) in LDS. Oct-task per thread:
// 8 consecutive pair-indices in both halves of one block -> 32 outputs.
// BARRIER-FREE: the (single) wave owns the whole LDS tile; a wave's DS
// instructions execute in order, so all cross-lane RAW/WAR hazards through
// LDS are ordered without __syncthreads.
template<int N>
__device__ __forceinline__ void lds_stage(char* ldsb, unsigned rb, unsigned tt,
                                          float p, float p1, float p2) {
    constexpr unsigned H = N / 2;
    constexpr int L2 = (N == 512) ? 4 : (N == 256) ? 3 : 2;   // log2(N/32)
    const unsigned b  = tt >> L2;
    const unsigned s  = tt & ((N / 32) - 1);
    const unsigned u0 = s * 8u;
    const unsigned bc = b * (unsigned)N;

    const unsigned Aj0  = swz(rb + 4u * (bc + u0));
    const unsigned Aj1  = swz(rb + 4u * (bc + H + u0));
    const unsigned Ajm0 = swz(rb + 4u * (bc + H - 8 - u0));
    const unsigned Ajm1 = swz(rb + 4u * (bc + N - 8 - u0));
    const unsigned Ae   = swz(rb + 4u * (bc + 2 * u0));
    const unsigned Aem  = swz(rb + 4u * (bc + 2 * H - 16 - 2 * u0));

    float j0[8], j1[8], jm0[8], jm1[8], e[16], em[16];
    *(float4*)&j0[0]  = ldsrd(ldsb, Aj0);        *(float4*)&j0[4]  = ldsrd(ldsb, Aj0 ^ 16u);
    *(float4*)&j1[0]  = ldsrd(ldsb, Aj1);        *(float4*)&j1[4]  = ldsrd(ldsb, Aj1 ^ 16u);
    *(float4*)&jm0[0] = ldsrd(ldsb, Ajm0);       *(float4*)&jm0[4] = ldsrd(ldsb, Ajm0 ^ 16u);
    *(float4*)&jm1[0] = ldsrd(ldsb, Ajm1);       *(float4*)&jm1[4] = ldsrd(ldsb, Ajm1 ^ 16u);
    *(float4*)&e[0]   = ldsrd(ldsb, Ae);         *(float4*)&e[4]   = ldsrd(ldsb, Ae ^ 16u);
    *(float4*)&e[8]   = ldsrd(ldsb, Ae ^ 32u);   *(float4*)&e[12]  = ldsrd(ldsb, Ae ^ 48u);
    *(float4*)&em[0]  = ldsrd(ldsb, Aem);        *(float4*)&em[4]  = ldsrd(ldsb, Aem ^ 16u);
    *(float4*)&em[8]  = ldsrd(ldsb, Aem ^ 32u);  *(float4*)&em[12] = ldsrd(ldsb, Aem ^ 48u);

    #pragma unroll
    for (int du = 0; du < 8; ++du) {
        {   // lo half
            float yj = j0[du], yjm = jm0[7 - du];
            float yej = e[2 * du], yejm = em[14 - 2 * du];
            float a0 = fmaf(p, yej - yj, yj);
            float a1 = fmaf(p, yejm - yjm, yjm);
            float d  = a1 - a0;
            j0[du]      = fmaf(p1, d, a0);
            jm0[7 - du] = fmaf(p1, -d, a1);
        }
        {   // hi half
            float zj = j1[du], zjm = jm1[7 - du];
            float zej = e[2 * du + 1], zejm = em[15 - 2 * du];
            float a0 = fmaf(p, zej - zj, zj);
            float a1 = fmaf(p, zejm - zjm, zjm);
            float d  = a1 - a0;
            j1[du]      = fmaf(p2, d, a0);
            jm1[7 - du] = fmaf(p2, -d, a1);
        }
    }
    // writes reuse the j-read addresses; same-wave DS ordering -> no barrier
    *(float4*)(ldsb + Aj0)          = *(const float4*)&j0[0];
    *(float4*)(ldsb + (Aj0 ^ 16u))  = *(const float4*)&j0[4];
    *(float4*)(ldsb + Aj1)          = *(const float4*)&j1[0];
    *(float4*)(ldsb + (Aj1 ^ 16u))  = *(const float4*)&j1[4];
    *(float4*)(ldsb + Ajm0)         = *(const float4*)&jm0[0];
    *(float4*)(ldsb + (Ajm0 ^ 16u)) = *(const float4*)&jm0[4];
    *(float4*)(ldsb + Ajm1)         = *(const float4*)&jm1[0];
    *(float4*)(ldsb + (Ajm1 ^ 16u)) = *(const float4*)&jm1[4];
}

// Stage of block size N <= 32 fully inside one thread's 32-float chunk.
template<int N>
__device__ __forceinline__ void reg_stage(float* arr, float p, float p1, float p2) {
    constexpr int H = N / 2;
    float tmp[32];
    #pragma unroll
    for (int bb = 0; bb < 32; bb += N) {
        #pragma unroll
        for (int u = 0; u < N / 4; ++u) {
            {   // lo half pair
                int j = bb + u, jm = bb + H - 1 - u;
                int ej = bb + 2 * u, ejm = bb + 2 * H - 2 - 2 * u;
                float a0 = fmaf(p, arr[ej]  - arr[j],  arr[j]);
                float a1 = fmaf(p, arr[ejm] - arr[jm], arr[jm]);
                tmp[j]  = fmaf(p1, a1 - a0, a0);
                tmp[jm] = fmaf(p1, a0 - a1, a1);
            }
            {   // hi half pair
                int j = bb + H + u, jm = bb + 2 * H - 1 - u;
                int ej = bb + 2 * u + 1, ejm = bb + 2 * H - 1 - 2 * u;
                float a0 = fmaf(p, arr[ej]  - arr[j],  arr[j]);
                float a1 = fmaf(p, arr[ejm] - arr[jm], arr[jm]);
                tmp[j]  = fmaf(p2, a1 - a0, a0);
                tmp[jm] = fmaf(p2, a0 - a1, a1);
            }
        }
    }
    #pragma unroll
    for (int v = 0; v < 32; ++v) arr[v] = tmp[v];
}

__global__ void bpp_prep(const float* __restrict__ logits, float* __restrict__ sp) {
    int i = threadIdx.x;
    if (i < 27) sp[i] = 1.0f / (1.0f + expf(-logits[i]));
}

template<bool USE_WS>
__global__ __launch_bounds__(TPB) void bpp_main(const float* __restrict__ x,
                                                float* __restrict__ out,
                                                const float* __restrict__ spws,
                                                const float* __restrict__ logits,
                                                unsigned ntiles) {
    __shared__ float lds[2 * 1024];             // 8 KB tile, no pad
    char* ldsb = (char*)lds;
    const unsigned l = threadIdx.x;             // lane id (block == one wave)

    float prl[27];
    if constexpr (!USE_WS) {
        #pragma unroll
        for (int i = 0; i < 27; ++i) prl[i] = 1.0f / (1.0f + expf(-logits[i]));
    }
    #define PV(i) (USE_WS ? spws[(i)] : prl[(i)])

    const unsigned row = l >> 5, tt = l & 31u;
    const unsigned rb = row * 4096u;

    // ---- persistent-wave grid-stride loop over 2-row tiles ----
    for (unsigned tile = blockIdx.x; tile < ntiles; tile += gridDim.x) {
        const size_t gbase = (size_t)tile * 2048u;

        // ---- entry: coalesced global -> LDS (1 KB per instruction) ----
        // WAR vs previous tile's exit ds_reads: same-wave in-order DS pipe.
        {
            const float4* __restrict__ gin = (const float4*)(x + gbase) + l;
            #pragma unroll
            for (int k = 0; k < 8; ++k) {
                float4 v = gin[k * 64];
                unsigned A = (unsigned)k * 1024u + l * 16u;
                *(float4*)(ldsb + swz(A)) = v;
            }
        }
        // no barrier: same-wave DS ordering covers the stage-1024 reads below

        // ---- stage 1024 (b=0 specialization), barrier-free ----
        {
            constexpr unsigned N = 1024, H = 512;
            const unsigned u0 = tt * 8u;
            const unsigned Aj0  = swz(rb + 4u * u0);
            const unsigned Aj1  = swz(rb + 4u * (H + u0));
            const unsigned Ajm0 = swz(rb + 4u * (H - 8 - u0));
            const unsigned Ajm1 = swz(rb + 4u * (N - 8 - u0));
            const unsigned Ae   = swz(rb + 4u * (2 * u0));
            const unsigned Aem  = swz(rb + 4u * (2 * H - 16 - 2 * u0));
            const float p = PV(24), p1 = PV(25), p2 = PV(26);

            float j0[8], j1[8], jm0[8], jm1[8], e[16], em[16];
            *(float4*)&j0[0]  = ldsrd(ldsb, Aj0);        *(float4*)&j0[4]  = ldsrd(ldsb, Aj0 ^ 16u);
            *(float4*)&j1[0]  = ldsrd(ldsb, Aj1);        *(float4*)&j1[4]  = ldsrd(ldsb, Aj1 ^ 16u);
            *(float4*)&jm0[0] = ldsrd(ldsb, Ajm0);       *(float4*)&jm0[4] = ldsrd(ldsb, Ajm0 ^ 16u);
            *(float4*)&jm1[0] = ldsrd(ldsb, Ajm1);       *(float4*)&jm1[4] = ldsrd(ldsb, Ajm1 ^ 16u);
            *(float4*)&e[0]   = ldsrd(ldsb, Ae);         *(float4*)&e[4]   = ldsrd(ldsb, Ae ^ 16u);
            *(float4*)&e[8]   = ldsrd(ldsb, Ae ^ 32u);   *(float4*)&e[12]  = ldsrd(ldsb, Ae ^ 48u);
            *(float4*)&em[0]  = ldsrd(ldsb, Aem);        *(float4*)&em[4]  = ldsrd(ldsb, Aem ^ 16u);
            *(float4*)&em[8]  = ldsrd(ldsb, Aem ^ 32u);  *(float4*)&em[12] = ldsrd(ldsb, Aem ^ 48u);

            #pragma unroll
            for (int du = 0; du < 8; ++du) {
                {
                    float yj = j0[du], yjm = jm0[7 - du];
                    float yej = e[2 * du], yejm = em[14 - 2 * du];
                    float a0 = fmaf(p, yej - yj, yj);
                    float a1 = fmaf(p, yejm - yjm, yjm);
                    float d  = a1 - a0;
                    j0[du]      = fmaf(p1, d, a0);
                    jm0[7 - du] = fmaf(p1, -d, a1);
                }
                {
                    float zj = j1[du], zjm = jm1[7 - du];
                    float zej = e[2 * du + 1], zejm = em[15 - 2 * du];
                    float a0 = fmaf(p, zej - zj, zj);
                    float a1 = fmaf(p, zejm - zjm, zjm);
                    float d  = a1 - a0;
                    j1[du]      = fmaf(p2, d, a0);
                    jm1[7 - du] = fmaf(p2, -d, a1);
                }
            }
            *(float4*)(ldsb + Aj0)          = *(const float4*)&j0[0];
            *(float4*)(ldsb + (Aj0 ^ 16u))  = *(const float4*)&j0[4];
            *(float4*)(ldsb + Aj1)          = *(const float4*)&j1[0];
            *(float4*)(ldsb + (Aj1 ^ 16u))  = *(const float4*)&j1[4];
            *(float4*)(ldsb + Ajm0)         = *(const float4*)&jm0[0];
            *(float4*)(ldsb + (Ajm0 ^ 16u)) = *(const float4*)&jm0[4];
            *(float4*)(ldsb + Ajm1)         = *(const float4*)&jm1[0];
            *(float4*)(ldsb + (Ajm1 ^ 16u)) = *(const float4*)&jm1[4];
        }
        lds_stage<512>(ldsb, rb, tt, PV(21), PV(22), PV(23));
        lds_stage<256>(ldsb, rb, tt, PV(18), PV(19), PV(20));
        lds_stage<128>(ldsb, rb, tt, PV(15), PV(16), PV(17));

        // ---- fused tail: stage 64 in registers + reg stages 32..4 ----
        {
            const unsigned q = tt & 1u;
            const unsigned Aown = swz(rb + 128u * tt);  // 128B-aligned, key const
            const unsigned Aoth = Aown ^ 128u;          // partner: bit7 not in key
            float own[32], oth[32];
            #pragma unroll
            for (int k = 0; k < 8; ++k) {
                *(float4*)&own[4 * k] = ldsrd(ldsb, Aown ^ (16u * k));
                *(float4*)&oth[4 * k] = ldsrd(ldsb, Aoth ^ (16u * k));
            }
            const float p = PV(12);
            const float q64 = q ? PV(14) : PV(13);
            float o[32];
            #pragma unroll
            for (int u = 0; u < 16; ++u) {
                float eja = q ? oth[2 * u + 1]  : own[2 * u];
                float ejb = q ? own[31 - 2 * u] : oth[30 - 2 * u];
                float yj = own[u], yjm = own[31 - u];
                float a0 = fmaf(p, eja - yj, yj);
                float a1 = fmaf(p, ejb - yjm, yjm);
                float d  = a1 - a0;
                o[u]      = fmaf(q64, d, a0);
                o[31 - u] = fmaf(q64, -d, a1);
            }
            reg_stage<32>(o, PV(9), PV(10), PV(11));
            reg_stage<16>(o, PV(6), PV(7),  PV(8));
            reg_stage< 8>(o, PV(3), PV(4),  PV(5));
            reg_stage< 4>(o, PV(0), PV(1),  PV(2));
            #pragma unroll
            for (int k = 0; k < 8; ++k)
                *(float4*)(ldsb + (Aown ^ (16u * k))) = *(const float4*)&o[4 * k];
        }

        // ---- exit: coalesced LDS -> global (1 KB per instruction) ----
        {
            float4* __restrict__ gout = (float4*)(out + gbase) + l;
            #pragma unroll
            for (int k = 0; k < 8; ++k) {
                unsigned A = (unsigned)k * 1024u + l * 16u;
                gout[k * 64] = *(const float4*)(ldsb + swz(A));
            }
        }
    }
    #undef PV
}

extern "C" void kernel_launch(void* const* d_in, const int* in_sizes, int n_in,
                              void* d_out, int out_size, void* d_ws, size_t ws_size,
                              hipStream_t stream) {
    const float* x      = (const float*)d_in[0];
    const float* logits = (const float*)d_in[1];
    float* out = (float*)d_out;
    unsigned tiles = (unsigned)(in_sizes[0] / 2048);
    unsigned grid = tiles < NBLK ? tiles : NBLK;
    if (ws_size >= 27 * sizeof(float)) {
        float* sp = (float*)d_ws;
        bpp_prep<<<dim3(1), dim3(32), 0, stream>>>(logits, sp);
        bpp_main<true><<<dim3(grid), dim3(TPB), 0, stream>>>(x, out, sp, logits, tiles);
    } else {
        bpp_main<false><<<dim3(grid), dim3(TPB), 0, stream>>>(x, out, nullptr, logits, tiles);
    }
}

// Round 13
// 130.654 us; speedup vs baseline: 1.3086x; 1.0403x over previous
//
#include <hip/hip_runtime.h>
#include <math.h>

#define TPB 128     // TWO independent waves per workgroup (beats the ~16 WG/CU cap)
#define ROWS 4      // 4 rows per block = 2 rows per wave; 16 KB LDS/block

// XOR-swizzle on linear LDS byte offset A (per-wave tile = 2 rows x 1024 f32
// = 8 KB). key = ((A>>8)^(A>>11))&7 applied to slot bits [4:7).  Involution.
// swz does NOT commute with '+': within a run whose unswizzled base has bits
// 4-6 clear and whose key bits are constant, swz(A+16k) = swz(A)^16k.
// Also: swz(X^128) = swz(X)^128 (bit 7 is not part of the key).
// Wave-1's half starts at +8192 B = multiple of the 128B bank stride, so the
// bank-balance proofs are translation-invariant across wave halves.
__device__ __forceinline__ unsigned swz(unsigned A) {
    return A ^ ((((A >> 8) ^ (A >> 11)) & 7u) << 4);
}

__device__ __forceinline__ float4 ldsrd(const char* ldsb, unsigned A) {
    return *(const float4*)(ldsb + A);
}

// One stage of block size N (512/256/128) in LDS. Oct-task per thread:
// 8 consecutive pair-indices in both halves of one block -> 32 outputs.
// BARRIER-FREE: each wave owns its 8 KB LDS half exclusively; a wave's DS
// instructions execute in order, so all cross-lane RAW/WAR hazards through
// LDS are ordered without __syncthreads.
template<int N>
__device__ __forceinline__ void lds_stage(char* ldsb, unsigned rb, unsigned tt,
                                          float p, float p1, float p2) {
    constexpr unsigned H = N / 2;
    constexpr int L2 = (N == 512) ? 4 : (N == 256) ? 3 : 2;   // log2(N/32)
    const unsigned b  = tt >> L2;
    const unsigned s  = tt & ((N / 32) - 1);
    const unsigned u0 = s * 8u;
    const unsigned bc = b * (unsigned)N;

    const unsigned Aj0  = swz(rb + 4u * (bc + u0));
    const unsigned Aj1  = swz(rb + 4u * (bc + H + u0));
    const unsigned Ajm0 = swz(rb + 4u * (bc + H - 8 - u0));
    const unsigned Ajm1 = swz(rb + 4u * (bc + N - 8 - u0));
    const unsigned Ae   = swz(rb + 4u * (bc + 2 * u0));
    const unsigned Aem  = swz(rb + 4u * (bc + 2 * H - 16 - 2 * u0));

    float j0[8], j1[8], jm0[8], jm1[8], e[16], em[16];
    *(float4*)&j0[0]  = ldsrd(ldsb, Aj0);        *(float4*)&j0[4]  = ldsrd(ldsb, Aj0 ^ 16u);
    *(float4*)&j1[0]  = ldsrd(ldsb, Aj1);        *(float4*)&j1[4]  = ldsrd(ldsb, Aj1 ^ 16u);
    *(float4*)&jm0[0] = ldsrd(ldsb, Ajm0);       *(float4*)&jm0[4] = ldsrd(ldsb, Ajm0 ^ 16u);
    *(float4*)&jm1[0] = ldsrd(ldsb, Ajm1);       *(float4*)&jm1[4] = ldsrd(ldsb, Ajm1 ^ 16u);
    *(float4*)&e[0]   = ldsrd(ldsb, Ae);         *(float4*)&e[4]   = ldsrd(ldsb, Ae ^ 16u);
    *(float4*)&e[8]   = ldsrd(ldsb, Ae ^ 32u);   *(float4*)&e[12]  = ldsrd(ldsb, Ae ^ 48u);
    *(float4*)&em[0]  = ldsrd(ldsb, Aem);        *(float4*)&em[4]  = ldsrd(ldsb, Aem ^ 16u);
    *(float4*)&em[8]  = ldsrd(ldsb, Aem ^ 32u);  *(float4*)&em[12] = ldsrd(ldsb, Aem ^ 48u);

    #pragma unroll
    for (int du = 0; du < 8; ++du) {
        {   // lo half
            float yj = j0[du], yjm = jm0[7 - du];
            float yej = e[2 * du], yejm = em[14 - 2 * du];
            float a0 = fmaf(p, yej - yj, yj);
            float a1 = fmaf(p, yejm - yjm, yjm);
            float d  = a1 - a0;
            j0[du]      = fmaf(p1, d, a0);
            jm0[7 - du] = fmaf(p1, -d, a1);
        }
        {   // hi half
            float zj = j1[du], zjm = jm1[7 - du];
            float zej = e[2 * du + 1], zejm = em[15 - 2 * du];
            float a0 = fmaf(p, zej - zj, zj);
            float a1 = fmaf(p, zejm - zjm, zjm);
            float d  = a1 - a0;
            j1[du]      = fmaf(p2, d, a0);
            jm1[7 - du] = fmaf(p2, -d, a1);
        }
    }
    // writes reuse the j-read addresses; same-wave DS ordering -> no barrier
    *(float4*)(ldsb + Aj0)          = *(const float4*)&j0[0];
    *(float4*)(ldsb + (Aj0 ^ 16u))  = *(const float4*)&j0[4];
    *(float4*)(ldsb + Aj1)          = *(const float4*)&j1[0];
    *(float4*)(ldsb + (Aj1 ^ 16u))  = *(const float4*)&j1[4];
    *(float4*)(ldsb + Ajm0)         = *(const float4*)&jm0[0];
    *(float4*)(ldsb + (Ajm0 ^ 16u)) = *(const float4*)&jm0[4];
    *(float4*)(ldsb + Ajm1)         = *(const float4*)&jm1[0];
    *(float4*)(ldsb + (Ajm1 ^ 16u)) = *(const float4*)&jm1[4];
}

// Stage of block size N <= 32 fully inside one thread's 32-float chunk.
template<int N>
__device__ __forceinline__ void reg_stage(float* arr, float p, float p1, float p2) {
    constexpr int H = N / 2;
    float tmp[32];
    #pragma unroll
    for (int bb = 0; bb < 32; bb += N) {
        #pragma unroll
        for (int u = 0; u < N / 4; ++u) {
            {   // lo half pair
                int j = bb + u, jm = bb + H - 1 - u;
                int ej = bb + 2 * u, ejm = bb + 2 * H - 2 - 2 * u;
                float a0 = fmaf(p, arr[ej]  - arr[j],  arr[j]);
                float a1 = fmaf(p, arr[ejm] - arr[jm], arr[jm]);
                tmp[j]  = fmaf(p1, a1 - a0, a0);
                tmp[jm] = fmaf(p1, a0 - a1, a1);
            }
            {   // hi half pair
                int j = bb + H + u, jm = bb + 2 * H - 1 - u;
                int ej = bb + 2 * u + 1, ejm = bb + 2 * H - 1 - 2 * u;
                float a0 = fmaf(p, arr[ej]  - arr[j],  arr[j]);
                float a1 = fmaf(p, arr[ejm] - arr[jm], arr[jm]);
                tmp[j]  = fmaf(p2, a1 - a0, a0);
                tmp[jm] = fmaf(p2, a0 - a1, a1);
            }
        }
    }
    #pragma unroll
    for (int v = 0; v < 32; ++v) arr[v] = tmp[v];
}

__global__ void bpp_prep(const float* __restrict__ logits, float* __restrict__ sp) {
    int i = threadIdx.x;
    if (i < 27) sp[i] = 1.0f / (1.0f + expf(-logits[i]));
}

template<bool USE_WS>
__global__ __launch_bounds__(TPB) void bpp_main(const float* __restrict__ x,
                                                float* __restrict__ out,
                                                const float* __restrict__ spws,
                                                const float* __restrict__ logits) {
    __shared__ float lds[ROWS * 1024];          // 16 KB: two independent 8 KB halves
    const unsigned t = threadIdx.x;
    const unsigned w = t >> 6, l = t & 63u;     // wave id, lane id
    char* ldsb = (char*)lds + w * 8192u;        // wave-private half
    const size_t gbase = (size_t)blockIdx.x * (ROWS * 1024) + w * 2048u;

    float prl[27];
    if constexpr (!USE_WS) {
        #pragma unroll
        for (int i = 0; i < 27; ++i) prl[i] = 1.0f / (1.0f + expf(-logits[i]));
    }
    #define PV(i) (USE_WS ? spws[(i)] : prl[(i)])

    // ---- entry: coalesced global -> LDS (1 KB per instruction) ----
    {
        const float4* __restrict__ gin = (const float4*)(x + gbase) + l;
        #pragma unroll
        for (int k = 0; k < 8; ++k) {
            float4 v = gin[k * 64];
            unsigned A = (unsigned)k * 1024u + l * 16u;
            *(float4*)(ldsb + swz(A)) = v;
        }
    }
    // no barrier: same-wave DS ordering covers the stage-1024 reads below

    const unsigned row = l >> 5, tt = l & 31u;
    const unsigned rb = row * 4096u;

    // ---- stages n = 1024..128 in LDS (logits rows 8..5), barrier-free ----
    {
        // stage 1024 (b=0 specialization of lds_stage)
        constexpr unsigned N = 1024, H = 512;
        const unsigned u0 = tt * 8u;
        const unsigned Aj0  = swz(rb + 4u * u0);
        const unsigned Aj1  = swz(rb + 4u * (H + u0));
        const unsigned Ajm0 = swz(rb + 4u * (H - 8 - u0));
        const unsigned Ajm1 = swz(rb + 4u * (N - 8 - u0));
        const unsigned Ae   = swz(rb + 4u * (2 * u0));
        const unsigned Aem  = swz(rb + 4u * (2 * H - 16 - 2 * u0));
        const float p = PV(24), p1 = PV(25), p2 = PV(26);

        float j0[8], j1[8], jm0[8], jm1[8], e[16], em[16];
        *(float4*)&j0[0]  = ldsrd(ldsb, Aj0);        *(float4*)&j0[4]  = ldsrd(ldsb, Aj0 ^ 16u);
        *(float4*)&j1[0]  = ldsrd(ldsb, Aj1);        *(float4*)&j1[4]  = ldsrd(ldsb, Aj1 ^ 16u);
        *(float4*)&jm0[0] = ldsrd(ldsb, Ajm0);       *(float4*)&jm0[4] = ldsrd(ldsb, Ajm0 ^ 16u);
        *(float4*)&jm1[0] = ldsrd(ldsb, Ajm1);       *(float4*)&jm1[4] = ldsrd(ldsb, Ajm1 ^ 16u);
        *(float4*)&e[0]   = ldsrd(ldsb, Ae);         *(float4*)&e[4]   = ldsrd(ldsb, Ae ^ 16u);
        *(float4*)&e[8]   = ldsrd(ldsb, Ae ^ 32u);   *(float4*)&e[12]  = ldsrd(ldsb, Ae ^ 48u);
        *(float4*)&em[0]  = ldsrd(ldsb, Aem);        *(float4*)&em[4]  = ldsrd(ldsb, Aem ^ 16u);
        *(float4*)&em[8]  = ldsrd(ldsb, Aem ^ 32u);  *(float4*)&em[12] = ldsrd(ldsb, Aem ^ 48u);

        #pragma unroll
        for (int du = 0; du < 8; ++du) {
            {
                float yj = j0[du], yjm = jm0[7 - du];
                float yej = e[2 * du], yejm = em[14 - 2 * du];
                float a0 = fmaf(p, yej - yj, yj);
                float a1 = fmaf(p, yejm - yjm, yjm);
                float d  = a1 - a0;
                j0[du]      = fmaf(p1, d, a0);
                jm0[7 - du] = fmaf(p1, -d, a1);
            }
            {
                float zj = j1[du], zjm = jm1[7 - du];
                float zej = e[2 * du + 1], zejm = em[15 - 2 * du];
                float a0 = fmaf(p, zej - zj, zj);
                float a1 = fmaf(p, zejm - zjm, zjm);
                float d  = a1 - a0;
                j1[du]      = fmaf(p2, d, a0);
                jm1[7 - du] = fmaf(p2, -d, a1);
            }
        }
        *(float4*)(ldsb + Aj0)          = *(const float4*)&j0[0];
        *(float4*)(ldsb + (Aj0 ^ 16u))  = *(const float4*)&j0[4];
        *(float4*)(ldsb + Aj1)          = *(const float4*)&j1[0];
        *(float4*)(ldsb + (Aj1 ^ 16u))  = *(const float4*)&j1[4];
        *(float4*)(ldsb + Ajm0)         = *(const float4*)&jm0[0];
        *(float4*)(ldsb + (Ajm0 ^ 16u)) = *(const float4*)&jm0[4];
        *(float4*)(ldsb + Ajm1)         = *(const float4*)&jm1[0];
        *(float4*)(ldsb + (Ajm1 ^ 16u)) = *(const float4*)&jm1[4];
    }
    lds_stage<512>(ldsb, rb, tt, PV(21), PV(22), PV(23));
    lds_stage<256>(ldsb, rb, tt, PV(18), PV(19), PV(20));
    lds_stage<128>(ldsb, rb, tt, PV(15), PV(16), PV(17));

    // ---- fused tail: stage 64 in registers + reg stages 32..4 ----
    // Thread owns chunk tt (cols [32tt, 32tt+32)); its 64-block partner half
    // is chunk tt^1. q = tt&1 selects lo/hi-half math (branchless selects).
    {
        const unsigned q = tt & 1u;
        const unsigned Aown = swz(rb + 128u * tt);  // 128B-aligned, key const
        const unsigned Aoth = Aown ^ 128u;          // partner: bit7 not in key
        float own[32], oth[32];
        #pragma unroll
        for (int k = 0; k < 8; ++k) {
            *(float4*)&own[4 * k] = ldsrd(ldsb, Aown ^ (16u * k));
            *(float4*)&oth[4 * k] = ldsrd(ldsb, Aoth ^ (16u * k));
        }
        const float p = PV(12);
        const float q64 = q ? PV(14) : PV(13);
        float o[32];
        #pragma unroll
        for (int u = 0; u < 16; ++u) {
            float eja = q ? oth[2 * u + 1]  : own[2 * u];
            float ejb = q ? own[31 - 2 * u] : oth[30 - 2 * u];
            float yj = own[u], yjm = own[31 - u];
            float a0 = fmaf(p, eja - yj, yj);
            float a1 = fmaf(p, ejb - yjm, yjm);
            float d  = a1 - a0;
            o[u]      = fmaf(q64, d, a0);
            o[31 - u] = fmaf(q64, -d, a1);
        }
        reg_stage<32>(o, PV(9), PV(10), PV(11));
        reg_stage<16>(o, PV(6), PV(7),  PV(8));
        reg_stage< 8>(o, PV(3), PV(4),  PV(5));
        reg_stage< 4>(o, PV(0), PV(1),  PV(2));
        // write back to own chunk (all lanes' reads above precede these writes
        // in the wave's in-order DS stream -> no WAR hazard)
        #pragma unroll
        for (int k = 0; k < 8; ++k)
            *(float4*)(ldsb + (Aown ^ (16u * k))) = *(const float4*)&o[4 * k];
    }

    // ---- exit: coalesced LDS -> global (1 KB per instruction) ----
    {
        float4* __restrict__ gout = (float4*)(out + gbase) + l;
        #pragma unroll
        for (int k = 0; k < 8; ++k) {
            unsigned A = (unsigned)k * 1024u + l * 16u;
            gout[k * 64] = *(const float4*)(ldsb + swz(A));
        }
    }
    #undef PV
}

extern "C" void kernel_launch(void* const* d_in, const int* in_sizes, int n_in,
                              void* d_out, int out_size, void* d_ws, size_t ws_size,
                              hipStream_t stream) {
    const float* x      = (const float*)d_in[0];
    const float* logits = (const float*)d_in[1];
    float* out = (float*)d_out;
    int rows = in_sizes[0] / 1024;
    int grid = rows / ROWS;
    if (ws_size >= 27 * sizeof(float)) {
        float* sp = (float*)d_ws;
        bpp_prep<<<dim3(1), dim3(32), 0, stream>>>(logits, sp);
        bpp_main<true><<<dim3(grid), dim3(TPB), 0, stream>>>(x, out, sp, logits);
    } else {
        bpp_main<false><<<dim3(grid), dim3(TPB), 0, stream>>>(x, out, nullptr, logits);
    }
}

// Round 14
// 124.379 us; speedup vs baseline: 1.3747x; 1.0504x over previous
//
#include <hip/hip_runtime.h>
#include <math.h>

#define TPB 64      // ONE wave per workgroup: best measured occupancy shape (R8)
#define ROWS 2      // 8 KB LDS per block

// XOR-swizzle on linear LDS byte offset A (tile = 2 rows x 1024 f32 = 8 KB).
// key = ((A>>8)^(A>>11))&7 applied to slot bits [4:7).  Involution.
// swz does NOT commute with '+': within a run whose unswizzled base has bits
// 4-6 clear and whose key bits are constant, swz(A+16k) = swz(A)^16k.
// Also: swz(X^128) = swz(X)^128 (bit 7 is not part of the key).
__device__ __forceinline__ unsigned swz(unsigned A) {
    return A ^ ((((A >> 8) ^ (A >> 11)) & 7u) << 4);
}

__device__ __forceinline__ float4 ldsrd(const char* ldsb, unsigned A) {
    return *(const float4*)(ldsb + A);
}

// One stage of block size N (512/256/128) in LDS. Oct-task per thread:
// 8 consecutive pair-indices in both halves of one block -> 32 outputs.
// BARRIER-FREE: the (single) wave owns the whole LDS tile; a wave's DS
// instructions execute in order, so all cross-lane RAW/WAR hazards through
// LDS are ordered without __syncthreads.
template<int N>
__device__ __forceinline__ void lds_stage(char* ldsb, unsigned rb, unsigned tt,
                                          float p, float p1, float p2) {
    constexpr unsigned H = N / 2;
    constexpr int L2 = (N == 512) ? 4 : (N == 256) ? 3 : 2;   // log2(N/32)
    const unsigned b  = tt >> L2;
    const unsigned s  = tt & ((N / 32) - 1);
    const unsigned u0 = s * 8u;
    const unsigned bc = b * (unsigned)N;

    const unsigned Aj0  = swz(rb + 4u * (bc + u0));
    const unsigned Aj1  = swz(rb + 4u * (bc + H + u0));
    const unsigned Ajm0 = swz(rb + 4u * (bc + H - 8 - u0));
    const unsigned Ajm1 = swz(rb + 4u * (bc + N - 8 - u0));
    const unsigned Ae   = swz(rb + 4u * (bc + 2 * u0));
    const unsigned Aem  = swz(rb + 4u * (bc + 2 * H - 16 - 2 * u0));

    float j0[8], j1[8], jm0[8], jm1[8], e[16], em[16];
    *(float4*)&j0[0]  = ldsrd(ldsb, Aj0);        *(float4*)&j0[4]  = ldsrd(ldsb, Aj0 ^ 16u);
    *(float4*)&j1[0]  = ldsrd(ldsb, Aj1);        *(float4*)&j1[4]  = ldsrd(ldsb, Aj1 ^ 16u);
    *(float4*)&jm0[0] = ldsrd(ldsb, Ajm0);       *(float4*)&jm0[4] = ldsrd(ldsb, Ajm0 ^ 16u);
    *(float4*)&jm1[0] = ldsrd(ldsb, Ajm1);       *(float4*)&jm1[4] = ldsrd(ldsb, Ajm1 ^ 16u);
    *(float4*)&e[0]   = ldsrd(ldsb, Ae);         *(float4*)&e[4]   = ldsrd(ldsb, Ae ^ 16u);
    *(float4*)&e[8]   = ldsrd(ldsb, Ae ^ 32u);   *(float4*)&e[12]  = ldsrd(ldsb, Ae ^ 48u);
    *(float4*)&em[0]  = ldsrd(ldsb, Aem);        *(float4*)&em[4]  = ldsrd(ldsb, Aem ^ 16u);
    *(float4*)&em[8]  = ldsrd(ldsb, Aem ^ 32u);  *(float4*)&em[12] = ldsrd(ldsb, Aem ^ 48u);

    #pragma unroll
    for (int du = 0; du < 8; ++du) {
        {   // lo half
            float yj = j0[du], yjm = jm0[7 - du];
            float yej = e[2 * du], yejm = em[14 - 2 * du];
            float a0 = fmaf(p, yej - yj, yj);
            float a1 = fmaf(p, yejm - yjm, yjm);
            float d  = a1 - a0;
            j0[du]      = fmaf(p1, d, a0);
            jm0[7 - du] = fmaf(p1, -d, a1);
        }
        {   // hi half
            float zj = j1[du], zjm = jm1[7 - du];
            float zej = e[2 * du + 1], zejm = em[15 - 2 * du];
            float a0 = fmaf(p, zej - zj, zj);
            float a1 = fmaf(p, zejm - zjm, zjm);
            float d  = a1 - a0;
            j1[du]      = fmaf(p2, d, a0);
            jm1[7 - du] = fmaf(p2, -d, a1);
        }
    }
    // writes reuse the j-read addresses; same-wave DS ordering -> no barrier
    *(float4*)(ldsb + Aj0)          = *(const float4*)&j0[0];
    *(float4*)(ldsb + (Aj0 ^ 16u))  = *(const float4*)&j0[4];
    *(float4*)(ldsb + Aj1)          = *(const float4*)&j1[0];
    *(float4*)(ldsb + (Aj1 ^ 16u))  = *(const float4*)&j1[4];
    *(float4*)(ldsb + Ajm0)         = *(const float4*)&jm0[0];
    *(float4*)(ldsb + (Ajm0 ^ 16u)) = *(const float4*)&jm0[4];
    *(float4*)(ldsb + Ajm1)         = *(const float4*)&jm1[0];
    *(float4*)(ldsb + (Ajm1 ^ 16u)) = *(const float4*)&jm1[4];
}

// Stage of block size N <= 32 fully inside one thread's 32-float chunk.
template<int N>
__device__ __forceinline__ void reg_stage(float* arr, float p, float p1, float p2) {
    constexpr int H = N / 2;
    float tmp[32];
    #pragma unroll
    for (int bb = 0; bb < 32; bb += N) {
        #pragma unroll
        for (int u = 0; u < N / 4; ++u) {
            {   // lo half pair
                int j = bb + u, jm = bb + H - 1 - u;
                int ej = bb + 2 * u, ejm = bb + 2 * H - 2 - 2 * u;
                float a0 = fmaf(p, arr[ej]  - arr[j],  arr[j]);
                float a1 = fmaf(p, arr[ejm] - arr[jm], arr[jm]);
                tmp[j]  = fmaf(p1, a1 - a0, a0);
                tmp[jm] = fmaf(p1, a0 - a1, a1);
            }
            {   // hi half pair
                int j = bb + H + u, jm = bb + 2 * H - 1 - u;
                int ej = bb + 2 * u + 1, ejm = bb + 2 * H - 1 - 2 * u;
                float a0 = fmaf(p, arr[ej]  - arr[j],  arr[j]);
                float a1 = fmaf(p, arr[ejm] - arr[jm], arr[jm]);
                tmp[j]  = fmaf(p2, a1 - a0, a0);
                tmp[jm] = fmaf(p2, a0 - a1, a1);
            }
        }
    }
    #pragma unroll
    for (int v = 0; v < 32; ++v) arr[v] = tmp[v];
}

__global__ void bpp_prep(const float* __restrict__ logits, float* __restrict__ sp) {
    int i = threadIdx.x;
    if (i < 27) sp[i] = 1.0f / (1.0f + expf(-logits[i]));
}

template<bool USE_WS>
__global__ __launch_bounds__(TPB) void bpp_main(const float* __restrict__ x,
                                                float* __restrict__ out,
                                                const float* __restrict__ spws,
                                                const float* __restrict__ logits) {
    __shared__ float lds[ROWS * 1024];
    char* ldsb = (char*)lds;
    const unsigned l = threadIdx.x;             // lane id (block == one wave)
    const size_t gbase = (size_t)blockIdx.x * (ROWS * 1024);

    float prl[27];
    if constexpr (!USE_WS) {
        #pragma unroll
        for (int i = 0; i < 27; ++i) prl[i] = 1.0f / (1.0f + expf(-logits[i]));
    }
    #define PV(i) (USE_WS ? spws[(i)] : prl[(i)])

    // ---- entry: coalesced global -> LDS (1 KB per instruction) ----
    {
        const float4* __restrict__ gin = (const float4*)(x + gbase) + l;
        #pragma unroll
        for (int k = 0; k < 8; ++k) {
            float4 v = gin[k * 64];
            unsigned A = (unsigned)k * 1024u + l * 16u;
            *(float4*)(ldsb + swz(A)) = v;
        }
    }
    // no barrier: same-wave DS ordering covers the stage-1024 reads below

    const unsigned row = l >> 5, tt = l & 31u;
    const unsigned rb = row * 4096u;

    // ---- stages n = 1024..128 in LDS (logits rows 8..5), barrier-free ----
    {
        // stage 1024 (b=0 specialization of lds_stage)
        constexpr unsigned N = 1024, H = 512;
        const unsigned u0 = tt * 8u;
        const unsigned Aj0  = swz(rb + 4u * u0);
        const unsigned Aj1  = swz(rb + 4u * (H + u0));
        const unsigned Ajm0 = swz(rb + 4u * (H - 8 - u0));
        const unsigned Ajm1 = swz(rb + 4u * (N - 8 - u0));
        const unsigned Ae   = swz(rb + 4u * (2 * u0));
        const unsigned Aem  = swz(rb + 4u * (2 * H - 16 - 2 * u0));
        const float p = PV(24), p1 = PV(25), p2 = PV(26);

        float j0[8], j1[8], jm0[8], jm1[8], e[16], em[16];
        *(float4*)&j0[0]  = ldsrd(ldsb, Aj0);        *(float4*)&j0[4]  = ldsrd(ldsb, Aj0 ^ 16u);
        *(float4*)&j1[0]  = ldsrd(ldsb, Aj1);        *(float4*)&j1[4]  = ldsrd(ldsb, Aj1 ^ 16u);
        *(float4*)&jm0[0] = ldsrd(ldsb, Ajm0);       *(float4*)&jm0[4] = ldsrd(ldsb, Ajm0 ^ 16u);
        *(float4*)&jm1[0] = ldsrd(ldsb, Ajm1);       *(float4*)&jm1[4] = ldsrd(ldsb, Ajm1 ^ 16u);
        *(float4*)&e[0]   = ldsrd(ldsb, Ae);         *(float4*)&e[4]   = ldsrd(ldsb, Ae ^ 16u);
        *(float4*)&e[8]   = ldsrd(ldsb, Ae ^ 32u);   *(float4*)&e[12]  = ldsrd(ldsb, Ae ^ 48u);
        *(float4*)&em[0]  = ldsrd(ldsb, Aem);        *(float4*)&em[4]  = ldsrd(ldsb, Aem ^ 16u);
        *(float4*)&em[8]  = ldsrd(ldsb, Aem ^ 32u);  *(float4*)&em[12] = ldsrd(ldsb, Aem ^ 48u);

        #pragma unroll
        for (int du = 0; du < 8; ++du) {
            {
                float yj = j0[du], yjm = jm0[7 - du];
                float yej = e[2 * du], yejm = em[14 - 2 * du];
                float a0 = fmaf(p, yej - yj, yj);
                float a1 = fmaf(p, yejm - yjm, yjm);
                float d  = a1 - a0;
                j0[du]      = fmaf(p1, d, a0);
                jm0[7 - du] = fmaf(p1, -d, a1);
            }
            {
                float zj = j1[du], zjm = jm1[7 - du];
                float zej = e[2 * du + 1], zejm = em[15 - 2 * du];
                float a0 = fmaf(p, zej - zj, zj);
                float a1 = fmaf(p, zejm - zjm, zjm);
                float d  = a1 - a0;
                j1[du]      = fmaf(p2, d, a0);
                jm1[7 - du] = fmaf(p2, -d, a1);
            }
        }
        *(float4*)(ldsb + Aj0)          = *(const float4*)&j0[0];
        *(float4*)(ldsb + (Aj0 ^ 16u))  = *(const float4*)&j0[4];
        *(float4*)(ldsb + Aj1)          = *(const float4*)&j1[0];
        *(float4*)(ldsb + (Aj1 ^ 16u))  = *(const float4*)&j1[4];
        *(float4*)(ldsb + Ajm0)         = *(const float4*)&jm0[0];
        *(float4*)(ldsb + (Ajm0 ^ 16u)) = *(const float4*)&jm0[4];
        *(float4*)(ldsb + Ajm1)         = *(const float4*)&jm1[0];
        *(float4*)(ldsb + (Ajm1 ^ 16u)) = *(const float4*)&jm1[4];
    }
    lds_stage<512>(ldsb, rb, tt, PV(21), PV(22), PV(23));
    lds_stage<256>(ldsb, rb, tt, PV(18), PV(19), PV(20));
    lds_stage<128>(ldsb, rb, tt, PV(15), PV(16), PV(17));

    // ---- fused tail: stage 64 in registers + reg stages 32..4 ----
    // Thread owns chunk tt (cols [32tt, 32tt+32)); its 64-block partner half
    // is chunk tt^1. q = tt&1 selects lo/hi-half math (branchless selects).
    {
        const unsigned q = tt & 1u;
        const unsigned Aown = swz(rb + 128u * tt);  // 128B-aligned, key const
        const unsigned Aoth = Aown ^ 128u;          // partner: bit7 not in key
        float own[32], oth[32];
        #pragma unroll
        for (int k = 0; k < 8; ++k) {
            *(float4*)&own[4 * k] = ldsrd(ldsb, Aown ^ (16u * k));
            *(float4*)&oth[4 * k] = ldsrd(ldsb, Aoth ^ (16u * k));
        }
        const float p = PV(12);
        const float q64 = q ? PV(14) : PV(13);
        float o[32];
        #pragma unroll
        for (int u = 0; u < 16; ++u) {
            float eja = q ? oth[2 * u + 1]  : own[2 * u];
            float ejb = q ? own[31 - 2 * u] : oth[30 - 2 * u];
            float yj = own[u], yjm = own[31 - u];
            float a0 = fmaf(p, eja - yj, yj);
            float a1 = fmaf(p, ejb - yjm, yjm);
            float d  = a1 - a0;
            o[u]      = fmaf(q64, d, a0);
            o[31 - u] = fmaf(q64, -d, a1);
        }
        reg_stage<32>(o, PV(9), PV(10), PV(11));
        reg_stage<16>(o, PV(6), PV(7),  PV(8));
        reg_stage< 8>(o, PV(3), PV(4),  PV(5));
        reg_stage< 4>(o, PV(0), PV(1),  PV(2));
        // write back to own chunk (all lanes' reads above precede these writes
        // in the wave's in-order DS stream -> no WAR hazard)
        #pragma unroll
        for (int k = 0; k < 8; ++k)
            *(float4*)(ldsb + (Aown ^ (16u * k))) = *(const float4*)&o[4 * k];
    }

    // ---- exit: coalesced LDS -> global (1 KB per instruction) ----
    {
        float4* __restrict__ gout = (float4*)(out + gbase) + l;
        #pragma unroll
        for (int k = 0; k < 8; ++k) {
            unsigned A = (unsigned)k * 1024u + l * 16u;
            gout[k * 64] = *(const float4*)(ldsb + swz(A));
        }
    }
    #undef PV
}

extern "C" void kernel_launch(void* const* d_in, const int* in_sizes, int n_in,
                              void* d_out, int out_size, void* d_ws, size_t ws_size,
                              hipStream_t stream) {
    const float* x      = (const float*)d_in[0];
    const float* logits = (const float*)d_in[1];
    float* out = (float*)d_out;
    int rows = in_sizes[0] / 1024;
    int grid = rows / ROWS;
    if (ws_size >= 27 * sizeof(float)) {
        float* sp = (float*)d_ws;
        bpp_prep<<<dim3(1), dim3(32), 0, stream>>>(logits, sp);
        bpp_main<true><<<dim3(grid), dim3(TPB), 0, stream>>>(x, out, sp, logits);
    } else {
        bpp_main<false><<<dim3(grid), dim3(TPB), 0, stream>>>(x, out, nullptr, logits);
    }
}